// Round 1
// 355.407 us; speedup vs baseline: 1.0029x; 1.0029x over previous
//
#include <hip/hip_runtime.h>
#include <hip/hip_bf16.h>

// Problem constants
#define BATCH   65536
#define HW      28
#define OHW     26
#define FEAT    676      // 26*26
#define HID     200
#define NCLS    10
#define MT      16       // images per block
#define NBLOCKS (BATCH / MT)   // 4096

typedef __attribute__((ext_vector_type(8))) __bf16 bf16x8;
typedef __attribute__((ext_vector_type(4))) float  f32x4;

__device__ __forceinline__ unsigned int pk2(float a, float b) {
  __hip_bfloat16 ha = __float2bfloat16(a), hb = __float2bfloat16(b);
  return (unsigned int)__builtin_bit_cast(unsigned short, ha)
       | ((unsigned int)__builtin_bit_cast(unsigned short, hb) << 16);
}

// ---------------------------------------------------------------------------
// A-fragment LDS layout (XOR-swizzled), shared by feat and hidT:
//   element (m, k) lives at ((k>>5)*64 + ((k>>3)&3)*16 + (m ^ ((k>>5)&7)))*8 + (k&7)
// GEMM read for lane = qd*16+ln at K-chunk kc:
//   base + (kc*64 + (lane ^ (kc&7)))*8   -> 64 distinct contiguous 16B chunks
//   per wave = conflict-free ds_read_b128 (bank = lane-derived, full spread).
// Conv/epilogue writes hit bank 4*((m&7)^(kc&7)) + (k&7)/2 -> kc spreads them.
// ---------------------------------------------------------------------------
__device__ __forceinline__ unsigned short* fslot(unsigned short* base, int m, int k) {
  const int kc = k >> 5;
  return base + ((kc * 64 + ((k >> 3) & 3) * 16 + (m ^ (kc & 7))) * 8) + (k & 7);
}

// ---------------------------------------------------------------------------
// prep_w1tf: w1 (676x200 f32) -> bf16 MFMA B-fragment order, coalesced reads.
// dst element ((kc*13+nt)*64 + qd*16 + ln)*8 + j  holds  w1[k][n],
//   n = nt*16+ln, k = kc*32+qd*8+j  (zero-padded)
// => each wave B-load in the GEMM is 64 lanes x 16B contiguous (1 KB).
// ---------------------------------------------------------------------------
__global__ __launch_bounds__(256) void prep_w1tf(const float* __restrict__ w1,
                                                 unsigned short* __restrict__ w1tf) {
  int idx = blockIdx.x * 256 + threadIdx.x;   // idx = k*208 + n
  if (idx >= 704 * 208) return;
  int k = idx / 208;
  int n = idx - k * 208;
  float v = (k < FEAT && n < HID) ? w1[k * HID + n] : 0.f;
  int nt = n >> 4, ln = n & 15;
  int kc = k >> 5, r = k & 31, qd = r >> 3, j = r & 7;
  size_t dst = ((size_t)(kc * 13 + nt) * 64 + qd * 16 + ln) * 8 + j;
  __hip_bfloat16 h = __float2bfloat16(v);
  w1tf[dst] = __builtin_bit_cast(unsigned short, h);
}

// w2 (200x10 f32) -> bf16 B-fragment order, K=224 N=16 padded. 7 KB.
__global__ __launch_bounds__(256) void prep_w2f(const float* __restrict__ w2,
                                                unsigned short* __restrict__ w2f) {
  int t = blockIdx.x * 256 + threadIdx.x;
  if (t >= 7 * 64 * 8) return;
  int j = t & 7, lane = (t >> 3) & 63, kc = t >> 9;
  int c = lane & 15;
  int k = kc * 32 + (lane >> 4) * 8 + j;
  float v = (c < NCLS && k < HID) ? w2[k * NCLS + c] : 0.f;
  __hip_bfloat16 h = __float2bfloat16(v);
  w2f[t] = __builtin_bit_cast(unsigned short, h);
}

// ---------------------------------------------------------------------------
// GEMM1 N-slice: 16x16x32 bf16 MFMA, A from swizzled-afrag LDS, B coalesced.
// C/D: col(n)=lane&15, row(m)=(lane>>4)*4+reg  [m89/m91 verified]
// Epilogue: relu(acc+b1) -> bf16 into hidA afrag slots.
// ---------------------------------------------------------------------------
template<int NT0, int NT>
__device__ __forceinline__ void gemm1_slice(
    const unsigned short* featA, const unsigned short* __restrict__ w1tf,
    const float* __restrict__ b1, unsigned short* hidA, int lane) {
  const int ln = lane & 15, qd = lane >> 4;
  f32x4 acc[NT];
  #pragma unroll
  for (int t = 0; t < NT; ++t) acc[t] = (f32x4){0.f, 0.f, 0.f, 0.f};
  for (int kc = 0; kc < 22; ++kc) {
    bf16x8 a = *(const bf16x8*)&featA[(kc * 64 + (lane ^ (kc & 7))) * 8];
    #pragma unroll
    for (int t = 0; t < NT; ++t) {
      bf16x8 b = *(const bf16x8*)(w1tf + ((size_t)(kc * 13 + NT0 + t) * 64 + lane) * 8);
      acc[t] = __builtin_amdgcn_mfma_f32_16x16x32_bf16(a, b, acc[t], 0, 0, 0);
    }
  }
  #pragma unroll
  for (int t = 0; t < NT; ++t) {
    const int n = (NT0 + t) * 16 + ln;
    if (n < HID) {
      const float bias = b1[n];
      const int kc2 = n >> 5, qd2 = (n >> 3) & 3, j2 = n & 7, c2 = kc2 & 7;
      #pragma unroll
      for (int rr = 0; rr < 4; ++rr) {
        const int m = qd * 4 + rr;
        float h = fmaxf(acc[t][rr] + bias, 0.f);
        __hip_bfloat16 hb = __float2bfloat16(h);
        hidA[(kc2 * 64 + qd2 * 16 + (m ^ c2)) * 8 + j2] =
            __builtin_bit_cast(unsigned short, hb);
      }
    }
  }
}

__global__ __launch_bounds__(256, 5) void fused2(
    const float* __restrict__ x, const float* __restrict__ cwp,
    const unsigned short* __restrict__ w1tf, const unsigned short* __restrict__ w2f,
    const float* __restrict__ b1, const float* __restrict__ b2,
    float* __restrict__ out) {
  __shared__ __align__(16) unsigned short featA[22 * 64 * 8];  // 22,528 B
  __shared__ __align__(16) unsigned short hidA [ 7 * 64 * 8];  //  7,168 B -> 29.7 KB, 5 blk/CU
  const int tid  = threadIdx.x;
  const int wave = tid >> 6;
  const int lane = tid & 63;

  // zero feat K-pad (k=676..703) and hid K-pad (k=200..223), all 16 rows.
  // Disjoint from conv/epilogue writes; made visible by the pre-GEMM barriers.
  for (int i = tid; i < MT * 14; i += 256) {
    int m = i / 14, d = i - m * 14;
    *(unsigned int*)fslot(featA, m, 676 + 2 * d) = 0u;
  }
  for (int i = tid; i < MT * 12; i += 256) {
    int m = i / 12, d = i - m * 12;
    *(unsigned int*)fslot(hidA, m, 200 + 2 * d) = 0u;
  }

  float cw[9];
  #pragma unroll
  for (int t = 0; t < 9; ++t) cw[t] = cwp[t];

  // ---- conv: per-wave private, straight from global (L1-backed), no barriers.
  // 364 = 4 images x 91 row-pair/col-quad items per wave, flattened to 6 iters.
  const float* xb = x + (size_t)blockIdx.x * (MT * 784);
  for (int t0 = 0; t0 < 364; t0 += 64) {
    const int t = t0 + lane;
    if (t < 364) {
      const int p   = (t * 721) >> 16;        // t / 91  (exact for t<364)
      const int r91 = t - 91 * p;
      const int iq  = (r91 * 9363) >> 16;     // r91 / 7 (exact for r91<91)
      const int jc  = r91 - 7 * iq;
      const int m   = 4 * p + wave;           // 4 waves fetch 4 consecutive images
      const float* xw = xb + m * 784;
      float in[4][6];
      const int c2 = (jc < 6) ? 4 : 2;        // jc==6: re-read cols 26,27 (unused), no OOB
      #pragma unroll
      for (int rr = 0; rr < 4; ++rr) {
        const float* rp = xw + (2 * iq + rr) * HW + 4 * jc;   // 16B aligned
        const float4 v = *(const float4*)rp;
        const float2 u = *(const float2*)(rp + c2);           // 8B aligned
        in[rr][0] = v.x; in[rr][1] = v.y; in[rr][2] = v.z; in[rr][3] = v.w;
        in[rr][4] = u.x; in[rr][5] = u.y;
      }
      float o[2][4];
      #pragma unroll
      for (int dr = 0; dr < 2; ++dr)
        #pragma unroll
        for (int dc = 0; dc < 4; ++dc) {
          float s = 0.f;
          #pragma unroll
          for (int di = 0; di < 3; ++di)
            #pragma unroll
            for (int dj = 0; dj < 3; ++dj)
              s += cw[di * 3 + dj] * in[dr + di][dc + dj];
          o[dr][dc] = s;
        }
      const int k0 = 52 * iq + 4 * jc;        // row 2iq, col 4jc; k0 % 4 == 0
      if (jc < 6) {
        // k0&7 in {0,4}: uint2 stays inside one 8-elem j-block, 8B aligned.
        *(uint2*)fslot(featA, m, k0) =
            make_uint2(pk2(o[0][0], o[0][1]), pk2(o[0][2], o[0][3]));
        *(unsigned int*)fslot(featA, m, k0 + OHW)     = pk2(o[1][0], o[1][1]);
        *(unsigned int*)fslot(featA, m, k0 + OHW + 2) = pk2(o[1][2], o[1][3]);
      } else {                                // cols 24,25 only
        *(unsigned int*)fslot(featA, m, k0)       = pk2(o[0][0], o[0][1]);
        *(unsigned int*)fslot(featA, m, k0 + OHW) = pk2(o[1][0], o[1][1]);
      }
    }
  }
  __syncthreads();   // feat complete (incl. pads) — barrier 1 of 2

  // ---- GEMM1: per-wave N-slice (13 tiles over 4 waves) ----
  switch (wave) {
    case 0:  gemm1_slice<0, 4>(featA, w1tf, b1, hidA, lane); break;
    case 1:  gemm1_slice<4, 3>(featA, w1tf, b1, hidA, lane); break;
    case 2:  gemm1_slice<7, 3>(featA, w1tf, b1, hidA, lane); break;
    default: gemm1_slice<10, 3>(featA, w1tf, b1, hidA, lane); break;
  }
  __syncthreads();   // hidA complete — barrier 2 of 2

  // ---- GEMM2: wave 0 only, one 16x16 MFMA tile over K=224 ----
  if (wave == 0) {
    const int ln = lane & 15, qd = lane >> 4;
    f32x4 acc2 = (f32x4){0.f, 0.f, 0.f, 0.f};
    #pragma unroll
    for (int kc = 0; kc < 7; ++kc) {
      bf16x8 a = *(const bf16x8*)&hidA[(kc * 64 + (lane ^ (kc & 7))) * 8];
      bf16x8 b = *(const bf16x8*)(w2f + ((size_t)kc * 64 + lane) * 8);
      acc2 = __builtin_amdgcn_mfma_f32_16x16x32_bf16(a, b, acc2, 0, 0, 0);
    }
    if (ln < NCLS) {
      const float bb = b2[ln];
      #pragma unroll
      for (int rr = 0; rr < 4; ++rr) {
        out[((size_t)blockIdx.x * MT + qd * 4 + rr) * NCLS + ln] = acc2[rr] + bb;
      }
    }
  }
}

extern "C" void kernel_launch(void* const* d_in, const int* in_sizes, int n_in,
                              void* d_out, int out_size, void* d_ws, size_t ws_size,
                              hipStream_t stream) {
  const float* x  = (const float*)d_in[0];
  const float* cw = (const float*)d_in[1];
  const float* w1 = (const float*)d_in[2];
  const float* b1 = (const float*)d_in[3];
  const float* w2 = (const float*)d_in[4];
  const float* b2 = (const float*)d_in[5];
  float* out = (float*)d_out;

  unsigned short* w1tf = (unsigned short*)d_ws;                       // 292,864 B
  unsigned short* w2f  = (unsigned short*)((char*)d_ws + 294912);     //   7,168 B

  hipLaunchKernelGGL(prep_w1tf, dim3((704 * 208 + 255) / 256), dim3(256), 0, stream,
                     w1, w1tf);
  hipLaunchKernelGGL(prep_w2f, dim3(14), dim3(256), 0, stream, w2, w2f);
  hipLaunchKernelGGL(fused2, dim3(NBLOCKS), dim3(256), 0, stream,
                     x, cw, w1tf, w2f, b1, b2, out);
}